// Round 3
// baseline (108.220 us; speedup 1.0000x reference)
//
#include <hip/hip_runtime.h>

// ProteinMapper: torsion angles -> rigid frames -> atom positions
// B=64, L=2048, 21 restypes, 8 groups, 14 atoms.

constexpr int NRES_TOTAL = 64 * 2048;     // 131072 residues
constexpr int NRT = 21;                   // restypes
constexpr int NG  = 8;                    // groups
constexpr int NA  = 14;                   // atoms

__global__ __launch_bounds__(256) void protein_mapper_kernel(
    const float* __restrict__ bb_rots,        // (B,L,3,3)
    const float* __restrict__ bb_trans,       // (B,L,3)
    const float* __restrict__ angles,         // (B,L,7,2)
    const int*   __restrict__ aatype,         // (B,L)
    const float* __restrict__ default_frames, // (21,8,4,4)
    const int*   __restrict__ group_idx,      // (21,14)
    const float* __restrict__ atom_mask,      // (21,14)
    const float* __restrict__ lit_positions,  // (21,14,3)
    float* __restrict__ out)                  // (B,L,14,3)
{
    // ---- stage small tables into LDS (≈17 KB) ----
    __shared__ float s_frames[NRT * NG * 16];   // 2688 f
    __shared__ int   s_gidx[NRT * NA];          // 294 i
    __shared__ float s_mask[NRT * NA];          // 294 f
    __shared__ float s_lit[NRT * NA * 3];       // 882 f

    for (int j = threadIdx.x; j < NRT * NG * 16; j += 256) s_frames[j] = default_frames[j];
    for (int j = threadIdx.x; j < NRT * NA; j += 256) {
        s_gidx[j] = group_idx[j];
        s_mask[j] = atom_mask[j];
    }
    for (int j = threadIdx.x; j < NRT * NA * 3; j += 256) s_lit[j] = lit_positions[j];
    __syncthreads();

    const int i = blockIdx.x * 256 + threadIdx.x;
    if (i >= NRES_TOTAL) return;

    const int aa = aatype[i];

    // ---- sin/cos per group (group 0 = backbone identity [s=0,c=1]) ----
    float sv[NG], cv[NG];
    sv[0] = 0.0f; cv[0] = 1.0f;
    const float2* angp = reinterpret_cast<const float2*>(angles + (size_t)i * 14);
    #pragma unroll
    for (int g = 1; g < NG; ++g) {
        float2 sc = angp[g - 1];
        sv[g] = sc.x;   // sin slot
        cv[g] = sc.y;   // cos slot
    }

    // ---- build local frames: fR = dR @ rotx(s,c), ft = dt ----
    // rotx rows: [1,0,0],[0,c,-s],[0,s,c]
    //   col0 = dR col0 ; col1 = c*dRcol1 + s*dRcol2 ; col2 = c*dRcol2 - s*dRcol1
    float R[NG][9], t[NG][3];
    const float* fr = s_frames + aa * (NG * 16);
    #pragma unroll
    for (int g = 0; g < NG; ++g) {
        const float* m = fr + g * 16;
        const float cg = cv[g], sg = sv[g];
        #pragma unroll
        for (int r = 0; r < 3; ++r) {
            const float a0 = m[r * 4 + 0], a1 = m[r * 4 + 1], a2 = m[r * 4 + 2];
            R[g][r * 3 + 0] = a0;
            R[g][r * 3 + 1] = cg * a1 + sg * a2;
            R[g][r * 3 + 2] = cg * a2 - sg * a1;
            t[g][r] = m[r * 4 + 3];
        }
    }

    // ---- compose chain for groups 5,6,7: (prev) ∘ (local g) ----
    // R[g] <- R[g-1] @ R[g] ; t[g] <- R[g-1] @ t[g] + t[g-1]
    #pragma unroll
    for (int g = 5; g < NG; ++g) {
        float Q[9], tq[3];
        #pragma unroll
        for (int r = 0; r < 3; ++r) {
            const float p0 = R[g - 1][r * 3 + 0];
            const float p1 = R[g - 1][r * 3 + 1];
            const float p2 = R[g - 1][r * 3 + 2];
            #pragma unroll
            for (int cdx = 0; cdx < 3; ++cdx)
                Q[r * 3 + cdx] = p0 * R[g][cdx] + p1 * R[g][3 + cdx] + p2 * R[g][6 + cdx];
            tq[r] = p0 * t[g][0] + p1 * t[g][1] + p2 * t[g][2] + t[g - 1][r];
        }
        #pragma unroll
        for (int k = 0; k < 9; ++k) R[g][k] = Q[k];
        t[g][0] = tq[0]; t[g][1] = tq[1]; t[g][2] = tq[2];
    }

    // ---- backbone frame (applied per-atom: bbR @ (Rc@lit + tc) + bbt) ----
    const float* br = bb_rots + (size_t)i * 9;
    const float b00 = br[0], b01 = br[1], b02 = br[2];
    const float b10 = br[3], b11 = br[4], b12 = br[5];
    const float b20 = br[6], b21 = br[7], b22 = br[8];
    const float* btp = bb_trans + (size_t)i * 3;
    const float bt0 = btp[0], bt1 = btp[1], bt2 = btp[2];

    // per-atom group index + mask (compile-time indexed registers)
    int   ga[NA];
    float mk[NA];
    #pragma unroll
    for (int a = 0; a < NA; ++a) {
        ga[a] = s_gidx[aa * NA + a];
        mk[a] = s_mask[aa * NA + a];
    }

    // ---- atoms: predicated (g,a) loop keeps all register indexing static ----
    float res[NA * 3];
    #pragma unroll
    for (int g = 0; g < NG; ++g) {
        #pragma unroll
        for (int a = 0; a < NA; ++a) {
            if (ga[a] == g) {
                const float lx = s_lit[(aa * NA + a) * 3 + 0];
                const float ly = s_lit[(aa * NA + a) * 3 + 1];
                const float lz = s_lit[(aa * NA + a) * 3 + 2];
                // local frame map
                const float px = R[g][0] * lx + R[g][1] * ly + R[g][2] * lz + t[g][0];
                const float py = R[g][3] * lx + R[g][4] * ly + R[g][5] * lz + t[g][1];
                const float pz = R[g][6] * lx + R[g][7] * ly + R[g][8] * lz + t[g][2];
                // backbone map
                const float qx = b00 * px + b01 * py + b02 * pz + bt0;
                const float qy = b10 * px + b11 * py + b12 * pz + bt1;
                const float qz = b20 * px + b21 * py + b22 * pz + bt2;
                const float m_ = mk[a];
                res[a * 3 + 0] = qx * m_;
                res[a * 3 + 1] = qy * m_;
                res[a * 3 + 2] = qz * m_;
            }
        }
    }

    // ---- store: 21 x float2 (per-residue offset 168 B -> always 8B-aligned) ----
    float2* op2 = reinterpret_cast<float2*>(out + (size_t)i * (NA * 3));
    #pragma unroll
    for (int k = 0; k < (NA * 3) / 2; ++k) {
        float2 v;
        v.x = res[2 * k + 0];
        v.y = res[2 * k + 1];
        op2[k] = v;
    }
}

extern "C" void kernel_launch(void* const* d_in, const int* in_sizes, int n_in,
                              void* d_out, int out_size, void* d_ws, size_t ws_size,
                              hipStream_t stream) {
    const float* bb_rots        = (const float*)d_in[0];
    const float* bb_trans       = (const float*)d_in[1];
    const float* angles         = (const float*)d_in[2];
    const int*   aatype         = (const int*)d_in[3];
    const float* default_frames = (const float*)d_in[4];
    const int*   group_idx      = (const int*)d_in[5];
    const float* atom_mask      = (const float*)d_in[6];
    const float* lit_positions  = (const float*)d_in[7];
    float* out = (float*)d_out;

    const int blocks = (NRES_TOTAL + 255) / 256;   // 512
    protein_mapper_kernel<<<blocks, 256, 0, stream>>>(
        bb_rots, bb_trans, angles, aatype,
        default_frames, group_idx, atom_mask, lit_positions, out);
}

// Round 5
// 93.456 us; speedup vs baseline: 1.1580x; 1.1580x over previous
//
#include <hip/hip_runtime.h>

// ProteinMapper: torsion angles -> rigid frames -> atom positions
// B=64, L=2048, 21 restypes, 8 groups, 14 atoms.
//
// Layout decisions (theory-driven, round 4):
//  - LDS tables TRANSPOSED to [element][aa]: per-element stride 21 -> distinct
//    aatypes land in distinct banks (old layout had stride 128 -> all aa on one
//    bank, ~20-way conflict on 96 reads/thread).
//  - Atom loop selects its frame via a 3-level cndmask tree (84 selects/atom)
//    instead of an exec-masked 8x14 scan (~2.2x fewer issued VALU ops), and
//    stores stream out immediately as float2 (no res[42] register buffer).

constexpr int NRES_TOTAL = 64 * 2048;     // 131072 residues
constexpr int NRT = 21;                   // restypes
constexpr int NG  = 8;                    // groups
constexpr int NA  = 14;                   // atoms

__global__ __launch_bounds__(256) void protein_mapper_kernel(
    const float* __restrict__ bb_rots,        // (B,L,3,3)
    const float* __restrict__ bb_trans,       // (B,L,3)
    const float* __restrict__ angles,         // (B,L,7,2)
    const int*   __restrict__ aatype,         // (B,L)
    const float* __restrict__ default_frames, // (21,8,4,4)
    const int*   __restrict__ group_idx,      // (21,14)
    const float* __restrict__ atom_mask,      // (21,14)
    const float* __restrict__ lit_positions,  // (21,14,3)
    float* __restrict__ out)                  // (B,L,14,3)
{
    // ---- stage small tables into LDS, TRANSPOSED to [element][aa] ----
    __shared__ float s_frames[128 * NRT];     // [g*16+r*4+c][aa]
    __shared__ int   s_gidx[NA * NRT];        // [a][aa]
    __shared__ float s_mask[NA * NRT];        // [a][aa]
    __shared__ float s_lit[NA * 3 * NRT];     // [a*3+c][aa]

    for (int n = threadIdx.x; n < NRT * 128; n += 256) {
        const int aa = n / 128, j = n % 128;
        s_frames[j * NRT + aa] = default_frames[n];
    }
    for (int n = threadIdx.x; n < NRT * NA; n += 256) {
        const int aa = n / NA, a = n % NA;
        s_gidx[a * NRT + aa] = group_idx[n];
        s_mask[a * NRT + aa] = atom_mask[n];
    }
    for (int n = threadIdx.x; n < NRT * NA * 3; n += 256) {
        const int aa = n / (NA * 3), k = n % (NA * 3);
        s_lit[k * NRT + aa] = lit_positions[n];
    }
    __syncthreads();

    const int i = blockIdx.x * 256 + threadIdx.x;
    if (i >= NRES_TOTAL) return;

    const int aa = aatype[i];

    // ---- sin/cos per group (group 0 = backbone identity [s=0,c=1]) ----
    float sv[NG], cv[NG];
    sv[0] = 0.0f; cv[0] = 1.0f;
    const float2* angp = reinterpret_cast<const float2*>(angles + (size_t)i * 14);
    #pragma unroll
    for (int g = 1; g < NG; ++g) {
        float2 sc = angp[g - 1];
        sv[g] = sc.x;   // sin slot
        cv[g] = sc.y;   // cos slot
    }

    // ---- build local frames: G[g][0..8] = dR @ rotx(s,c), G[g][9..11] = dt ----
    // rotx: col0 = dRcol0 ; col1 = c*dRcol1 + s*dRcol2 ; col2 = c*dRcol2 - s*dRcol1
    float G[NG][12];
    #pragma unroll
    for (int g = 0; g < NG; ++g) {
        const float cg = cv[g], sg = sv[g];
        #pragma unroll
        for (int r = 0; r < 3; ++r) {
            const float a0 = s_frames[(g * 16 + r * 4 + 0) * NRT + aa];
            const float a1 = s_frames[(g * 16 + r * 4 + 1) * NRT + aa];
            const float a2 = s_frames[(g * 16 + r * 4 + 2) * NRT + aa];
            const float a3 = s_frames[(g * 16 + r * 4 + 3) * NRT + aa];
            G[g][r * 3 + 0] = a0;
            G[g][r * 3 + 1] = cg * a1 + sg * a2;
            G[g][r * 3 + 2] = cg * a2 - sg * a1;
            G[g][9 + r]     = a3;
        }
    }

    // ---- compose chain for groups 5,6,7: G[g] <- G[g-1] ∘ G[g] ----
    #pragma unroll
    for (int g = 5; g < NG; ++g) {
        float Q[12];
        #pragma unroll
        for (int r = 0; r < 3; ++r) {
            const float p0 = G[g - 1][r * 3 + 0];
            const float p1 = G[g - 1][r * 3 + 1];
            const float p2 = G[g - 1][r * 3 + 2];
            #pragma unroll
            for (int cdx = 0; cdx < 3; ++cdx)
                Q[r * 3 + cdx] = p0 * G[g][cdx] + p1 * G[g][3 + cdx] + p2 * G[g][6 + cdx];
            Q[9 + r] = p0 * G[g][9] + p1 * G[g][10] + p2 * G[g][11] + G[g - 1][9 + r];
        }
        #pragma unroll
        for (int k = 0; k < 12; ++k) G[g][k] = Q[k];
    }

    // ---- backbone frame (applied per-atom: bbR @ (Rsel@lit + tsel) + bbt) ----
    const float* br = bb_rots + (size_t)i * 9;
    const float b00 = br[0], b01 = br[1], b02 = br[2];
    const float b10 = br[3], b11 = br[4], b12 = br[5];
    const float b20 = br[6], b21 = br[7], b22 = br[8];
    const float* btp = bb_trans + (size_t)i * 3;
    const float bt0 = btp[0], bt1 = btp[1], bt2 = btp[2];

    // per-atom: 3-level cndmask tree selects G[ga] (static element indexing)
    auto atom_pos = [&](int a, float& qx, float& qy, float& qz) {
        const int   ga = s_gidx[a * NRT + aa];
        const float m_ = s_mask[a * NRT + aa];
        const float lx = s_lit[(a * 3 + 0) * NRT + aa];
        const float ly = s_lit[(a * 3 + 1) * NRT + aa];
        const float lz = s_lit[(a * 3 + 2) * NRT + aa];
        const bool b0_ = ga & 1, b1_ = ga & 2, b2_ = ga & 4;
        float S[12];
        #pragma unroll
        for (int e = 0; e < 12; ++e) {
            const float t0 = b0_ ? G[1][e] : G[0][e];
            const float t1 = b0_ ? G[3][e] : G[2][e];
            const float t2 = b0_ ? G[5][e] : G[4][e];
            const float t3 = b0_ ? G[7][e] : G[6][e];
            const float u0 = b1_ ? t1 : t0;
            const float u1 = b1_ ? t3 : t2;
            S[e] = b2_ ? u1 : u0;
        }
        const float px = S[0] * lx + S[1] * ly + S[2] * lz + S[9];
        const float py = S[3] * lx + S[4] * ly + S[5] * lz + S[10];
        const float pz = S[6] * lx + S[7] * ly + S[8] * lz + S[11];
        qx = (b00 * px + b01 * py + b02 * pz + bt0) * m_;
        qy = (b10 * px + b11 * py + b12 * pz + bt1) * m_;
        qz = (b20 * px + b21 * py + b22 * pz + bt2) * m_;
    };

    // ---- atoms in pairs -> 3 float2 stores per pair (offset 168 B, 8B-aligned) ----
    float2* op2 = reinterpret_cast<float2*>(out + (size_t)i * (NA * 3));
    #pragma unroll
    for (int ap = 0; ap < NA / 2; ++ap) {
        float qx0, qy0, qz0, qx1, qy1, qz1;
        atom_pos(2 * ap + 0, qx0, qy0, qz0);
        atom_pos(2 * ap + 1, qx1, qy1, qz1);
        float2 v0; v0.x = qx0; v0.y = qy0;
        float2 v1; v1.x = qz0; v1.y = qx1;
        float2 v2; v2.x = qy1; v2.y = qz1;
        op2[3 * ap + 0] = v0;
        op2[3 * ap + 1] = v1;
        op2[3 * ap + 2] = v2;
    }
}

extern "C" void kernel_launch(void* const* d_in, const int* in_sizes, int n_in,
                              void* d_out, int out_size, void* d_ws, size_t ws_size,
                              hipStream_t stream) {
    const float* bb_rots        = (const float*)d_in[0];
    const float* bb_trans       = (const float*)d_in[1];
    const float* angles         = (const float*)d_in[2];
    const int*   aatype         = (const int*)d_in[3];
    const float* default_frames = (const float*)d_in[4];
    const int*   group_idx      = (const int*)d_in[5];
    const float* atom_mask      = (const float*)d_in[6];
    const float* lit_positions  = (const float*)d_in[7];
    float* out = (float*)d_out;

    const int blocks = (NRES_TOTAL + 255) / 256;   // 512
    protein_mapper_kernel<<<blocks, 256, 0, stream>>>(
        bb_rots, bb_trans, angles, aatype,
        default_frames, group_idx, atom_mask, lit_positions, out);
}